// Round 6
// baseline (243.247 us; speedup 1.0000x reference)
//
#include <hip/hip_runtime.h>

#define E_TOTAL 262144
#define TPB 256
#define NBLK 1024            // E / CHUNK
#define EPT 4
#define GPB (TPB/4)          // pairs per block per k-iter = 64
#define CHUNK (GPB*EPT)      // 256 pairs per block, locally type-sorted
#define W0S 516              // per-type float stride for sW0 (512 + 4 pad)
#define W1S 260              // per-type float stride for sW1 (256 + 4 pad)

__device__ __forceinline__ float silu_f(float x) {
    return x / (1.0f + __expf(-x));
}

// ---- deterministic per-chunk counting sort by pair type ----
// perm[chunk slot] = pair_index | (type << 20). Stable within chunk.
__global__ __launch_bounds__(64)
void nep_sort(const int* __restrict__ ij, int* __restrict__ perm)
{
    __shared__ unsigned char sty[CHUNK];
    __shared__ int soff[16];
    const int tid = threadIdx.x;
    const int base = blockIdx.x * CHUNK;
    for (int i = tid; i < CHUNK; i += 64) sty[i] = (unsigned char)ij[base + i];
    __syncthreads();
    if (tid < 16) {
        int c = 0;
        for (int i = 0; i < CHUNK; i++) c += (sty[i] == tid);
        soff[tid] = c;
    }
    __syncthreads();
    if (tid == 0) {
        int acc = 0;
        #pragma unroll
        for (int t = 0; t < 16; t++) { int c = soff[t]; soff[t] = acc; acc += c; }
    }
    __syncthreads();
    if (tid < 16) {
        int o = soff[tid];
        for (int i = 0; i < CHUNK; i++)
            if (sty[i] == tid) { perm[base + o] = (base + i) | (tid << 20); o++; }
    }
}

// 4 lanes cooperate on one pair; lane (tid&3) owns channels h = lane*8 .. lane*8+7.
// Pairs are visited in type-sorted order (via perm) -> wave-uniform types ->
// W0/W1 LDS reads broadcast (no bank conflicts).
template<int PHASE>
__global__ __launch_bounds__(TPB, 4)
void nep_main(const int* __restrict__ perm,
              const float* __restrict__ fn,
              const float* __restrict__ W0g,
              const float* __restrict__ W1g,
              const float* __restrict__ ab1,
              const float* __restrict__ ab2,
              float* __restrict__ partial,
              float* __restrict__ ab_out,
              const float* __restrict__ gamma,
              const float* __restrict__ beta,
              const int* __restrict__ norm,
              unsigned int* __restrict__ counter,
              float* __restrict__ out)
{
    __shared__ __align__(16) float sW0[16 * W0S];
    __shared__ __align__(16) float sW1[(PHASE >= 1) ? 16 * W1S : 4];
    __shared__ float sAB1[64];
    __shared__ float sAB2[16];
    __shared__ float sredS[4][32];
    __shared__ float sredQ[4][32];
    __shared__ float fsum[TPB];
    __shared__ float fsq [TPB];
    __shared__ unsigned int slast;

    const int tid = threadIdx.x;
    const int bid = blockIdx.x;
    const int lane4 = tid & 3;
    const int grp = tid >> 2;

    // Stage W0 -> LDS, XOR block swizzle (reader lane4 k reads block j^k).
    {
        const float4* W04 = (const float4*)W0g;
        #pragma unroll
        for (int i = 0; i < 8; i++) {
            int g4 = tid + i * TPB;              // 0..2047
            float4 v = W04[g4];
            int t = g4 >> 7;
            int h = (g4 >> 2) & 31;
            int j = g4 & 3;
            int js = j ^ ((h >> 3) & 3);
            *(float4*)&sW0[t * W0S + h * 16 + js * 4] = v;
        }
    }
    if constexpr (PHASE >= 1) {
        // W1 global [t][n][h] -> LDS [t][(h&7)*32 + (h>>3)*8 + n]
        // reader lane4 reads (h>>3)==lane4 segment: 4 lanes -> 4 distinct bank quads.
        const float4* W14 = (const float4*)W1g;
        #pragma unroll
        for (int i = 0; i < 4; i++) {
            int g4 = tid + i * TPB;              // 0..1023
            float4 v = W14[g4];
            int g = g4 * 4;
            int t = g >> 8;
            int n = (g >> 5) & 7;
            int h0 = g & 31;                     // 4 consecutive h
            #pragma unroll
            for (int dd = 0; dd < 4; dd++) {
                int h = h0 + dd;
                float val = (dd == 0) ? v.x : (dd == 1) ? v.y : (dd == 2) ? v.z : v.w;
                sW1[t * W1S + (h & 7) * 32 + (h >> 3) * 8 + n] = val;
            }
        }
        if (tid < 64) sAB1[tid] = ab1[tid];
    }
    if constexpr (PHASE == 2) {
        if (tid < 16) sAB2[tid] = ab2[tid];
    }
    __syncthreads();

    // reg-cache BN1 affine for my 8 channels; BN2 affine (phase 2)
    float abA[8], abB[8];
    if constexpr (PHASE >= 1) {
        #pragma unroll
        for (int c = 0; c < 8; c++) {
            abA[c] = sAB1[lane4 * 8 + c];
            abB[c] = sAB1[32 + lane4 * 8 + c];
        }
    }
    float a2A[8], a2B[8];
    if constexpr (PHASE == 2) {
        #pragma unroll
        for (int n = 0; n < 8; n++) { a2A[n] = sAB2[n]; a2B[n] = sAB2[8 + n]; }
    }

    float s1[8], s2[8];
    #pragma unroll
    for (int c = 0; c < 8; c++) { s1[c] = 0.f; s2[c] = 0.f; }

    // two-deep pipeline: perm value 2 ahead, fn 1 ahead
    const int sl = bid * CHUNK + grp;
    int pvA = perm[sl];
    int pvB = perm[sl + GPB];
    {
    }
    int qA0 = pvA & 0xFFFFF;
    const float4* f40 = (const float4*)(fn + (size_t)qA0 * 16);
    float4 fa = f40[0], fb = f40[1], fc = f40[2], fd = f40[3];

    #pragma unroll 1
    for (int k = 0; k < EPT; k++) {
        const int t = pvA >> 20;
        const int q = pvA & 0xFFFFF;

        int pvC = pvB;
        if (k + 2 < EPT) pvC = perm[sl + (k + 2) * GPB];
        float4 na = fa, nb = fb, nc = fc, nd = fd;
        if (k + 1 < EPT) {
            int qn = pvB & 0xFFFFF;
            const float4* g4p = (const float4*)(fn + (size_t)qn * 16);
            na = g4p[0]; nb = g4p[1]; nc = g4p[2]; nd = g4p[3];
        }

        const float* w0t = &sW0[t * W0S];

        float o2[8];
        if constexpr (PHASE >= 1) {
            #pragma unroll
            for (int n = 0; n < 8; n++) o2[n] = 0.f;
        }

        #pragma unroll
        for (int hh = 0; hh < 8; hh++) {
            const int h = lane4 * 8 + hh;
            const float* wr = w0t + h * 16;
            const int x = lane4;                 // == (h>>3)&3
            float4 wA = *(const float4*)(wr + ((0 ^ x) << 2));
            float4 wB = *(const float4*)(wr + ((1 ^ x) << 2));
            float4 wC = *(const float4*)(wr + ((2 ^ x) << 2));
            float4 wD = *(const float4*)(wr + ((3 ^ x) << 2));
            float d = wA.x * fa.x + wA.y * fa.y + wA.z * fa.z + wA.w * fa.w
                    + wB.x * fb.x + wB.y * fb.y + wB.z * fb.z + wB.w * fb.w
                    + wC.x * fc.x + wC.y * fc.y + wC.z * fc.z + wC.w * fc.w
                    + wD.x * fd.x + wD.y * fd.y + wD.z * fd.z + wD.w * fd.w;
            if constexpr (PHASE == 0) {
                s1[hh] += d;
                s2[hh] += d * d;
            } else {
                float xv = abA[hh] * d + abB[hh];
                float a = silu_f(xv);
                const float* wn = &sW1[t * W1S + hh * 32 + lane4 * 8];
                float4 pA = *(const float4*)(wn);
                float4 pB = *(const float4*)(wn + 4);
                o2[0] += pA.x * a; o2[1] += pA.y * a; o2[2] += pA.z * a; o2[3] += pA.w * a;
                o2[4] += pB.x * a; o2[5] += pB.y * a; o2[6] += pB.z * a; o2[7] += pB.w * a;
            }
        }

        if constexpr (PHASE >= 1) {
            #pragma unroll
            for (int n = 0; n < 8; n++) {
                o2[n] += __shfl_xor(o2[n], 1, 64);
                o2[n] += __shfl_xor(o2[n], 2, 64);
            }
        }
        if constexpr (PHASE == 1) {
            if (lane4 == 0) {
                #pragma unroll
                for (int n = 0; n < 8; n++) { s1[n] += o2[n]; s2[n] += o2[n] * o2[n]; }
            }
        }
        if constexpr (PHASE == 2) {
            float r0 = silu_f(a2A[0] * o2[0] + a2B[0]);
            float r1 = silu_f(a2A[1] * o2[1] + a2B[1]);
            float r2 = silu_f(a2A[2] * o2[2] + a2B[2]);
            float r3 = silu_f(a2A[3] * o2[3] + a2B[3]);
            float r4 = silu_f(a2A[4] * o2[4] + a2B[4]);
            float r5 = silu_f(a2A[5] * o2[5] + a2B[5]);
            float r6 = silu_f(a2A[6] * o2[6] + a2B[6]);
            float r7 = silu_f(a2A[7] * o2[7] + a2B[7]);
            float e0 = (lane4 == 0) ? r0 : (lane4 == 1) ? r2 : (lane4 == 2) ? r4 : r6;
            float e1 = (lane4 == 0) ? r1 : (lane4 == 1) ? r3 : (lane4 == 2) ? r5 : r7;
            *(float2*)(out + (size_t)q * 8 + lane4 * 2) = make_float2(e0, e1);
        }

        pvA = pvB; pvB = pvC;
        fa = na; fb = nb; fc = nc; fd = nd;
    }

    if constexpr (PHASE == 0) {
        #pragma unroll
        for (int c = 0; c < 8; c++) {
            float v1 = s1[c], v2 = s2[c];
            v1 += __shfl_xor(v1, 4, 64);  v2 += __shfl_xor(v2, 4, 64);
            v1 += __shfl_xor(v1, 8, 64);  v2 += __shfl_xor(v2, 8, 64);
            v1 += __shfl_xor(v1, 16, 64); v2 += __shfl_xor(v2, 16, 64);
            v1 += __shfl_xor(v1, 32, 64); v2 += __shfl_xor(v2, 32, 64);
            s1[c] = v1; s2[c] = v2;
        }
        const int wid = tid >> 6;
        if ((tid & 63) < 4) {
            #pragma unroll
            for (int c = 0; c < 8; c++) {
                sredS[wid][lane4 * 8 + c] = s1[c];
                sredQ[wid][lane4 * 8 + c] = s2[c];
            }
        }
        __syncthreads();
        if (tid < 32) {
            float a = sredS[0][tid] + sredS[1][tid] + sredS[2][tid] + sredS[3][tid];
            float b = sredQ[0][tid] + sredQ[1][tid] + sredQ[2][tid] + sredQ[3][tid];
            partial[bid * 64 + tid]      = a;
            partial[bid * 64 + 32 + tid] = b;
        }
    }
    if constexpr (PHASE == 1) {
        #pragma unroll
        for (int c = 0; c < 8; c++) {
            float v1 = s1[c], v2 = s2[c];
            v1 += __shfl_xor(v1, 4, 64);  v2 += __shfl_xor(v2, 4, 64);
            v1 += __shfl_xor(v1, 8, 64);  v2 += __shfl_xor(v2, 8, 64);
            v1 += __shfl_xor(v1, 16, 64); v2 += __shfl_xor(v2, 16, 64);
            v1 += __shfl_xor(v1, 32, 64); v2 += __shfl_xor(v2, 32, 64);
            s1[c] = v1; s2[c] = v2;
        }
        const int wid = tid >> 6;
        if ((tid & 63) == 0) {
            #pragma unroll
            for (int n = 0; n < 8; n++) { sredS[wid][n] = s1[n]; sredQ[wid][n] = s2[n]; }
        }
        __syncthreads();
        if (tid < 8) {
            float a = sredS[0][tid] + sredS[1][tid] + sredS[2][tid] + sredS[3][tid];
            float b = sredQ[0][tid] + sredQ[1][tid] + sredQ[2][tid] + sredQ[3][tid];
            partial[bid * 16 + tid]     = a;
            partial[bid * 16 + 8 + tid] = b;
        }
    }

    // ---- last-block deterministic finalize ----
    if constexpr (PHASE <= 1) {
        __threadfence();
        if (tid == 0) slast = atomicAdd(counter, 1u);
        __syncthreads();
        if (slast == NBLK - 1) {
            __threadfence();
            constexpr int NS = (PHASE == 0) ? 32 : 8;
            constexpr int JW = TPB / NS;
            const int c = tid & (NS - 1);
            const int j = tid / NS;
            float s = 0.f, q = 0.f;
            for (int blk = j; blk < NBLK; blk += JW) {
                s += partial[blk * (2 * NS) + c];
                q += partial[blk * (2 * NS) + NS + c];
            }
            fsum[j * NS + c] = s; fsq[j * NS + c] = q;
            __syncthreads();
            if (tid < NS) {
                float st = 0.f, qt = 0.f;
                #pragma unroll
                for (int jj = 0; jj < JW; jj++) { st += fsum[jj * NS + c]; qt += fsq[jj * NS + c]; }
                const float invE = 1.0f / (float)E_TOTAL;
                float mean = st * invE;
                float var  = qt * invE - mean * mean;
                float inv  = rsqrtf(var + 1e-5f);
                float a, b;
                if (*norm) {
                    a = gamma[c] * inv;
                    b = beta[c] - mean * a;
                } else {
                    a = 1.f; b = 0.f;
                }
                ab_out[c] = a;
                ab_out[NS + c] = b;
            }
        }
    }
}

extern "C" void kernel_launch(void* const* d_in, const int* in_sizes, int n_in,
                              void* d_out, int out_size, void* d_ws, size_t ws_size,
                              hipStream_t stream)
{
    const int*   ij   = (const int*)d_in[0];
    const float* fn   = (const float*)d_in[1];
    const float* W0   = (const float*)d_in[2];
    const float* W1   = (const float*)d_in[3];
    const float* g1   = (const float*)d_in[4];
    const float* b1   = (const float*)d_in[5];
    const float* g2   = (const float*)d_in[6];
    const float* b2   = (const float*)d_in[7];
    const int*   norm = (const int*)d_in[8];
    float* out = (float*)d_out;

    int*   perm = (int*)d_ws;                        // E ints (1 MB)
    float* p1  = (float*)(perm + E_TOTAL);           // NBLK * 64 floats
    float* p2  = p1 + NBLK * 64;                     // NBLK * 16 floats
    float* ab1 = p2 + NBLK * 16;                     // 64 floats
    float* ab2 = ab1 + 64;                           // 16 floats
    unsigned int* ctr = (unsigned int*)(ab2 + 16);   // 2 uints

    hipMemsetAsync(ctr, 0, 2 * sizeof(unsigned int), stream);

    nep_sort<<<NBLK, 64, 0, stream>>>(ij, perm);

    nep_main<0><<<NBLK, TPB, 0, stream>>>(perm, fn, W0, W1, nullptr, nullptr,
                                          p1, ab1, g1, b1, norm, ctr, nullptr);
    nep_main<1><<<NBLK, TPB, 0, stream>>>(perm, fn, W0, W1, ab1, nullptr,
                                          p2, ab2, g2, b2, norm, ctr + 1, nullptr);
    nep_main<2><<<NBLK, TPB, 0, stream>>>(perm, fn, W0, W1, ab1, ab2,
                                          nullptr, nullptr, nullptr, nullptr, nullptr, nullptr, out);
}

// Round 7
// 94.229 us; speedup vs baseline: 2.5814x; 2.5814x over previous
//
#include <hip/hip_runtime.h>

#define E_TOTAL 262144
#define TPB 256
#define NBLK 1024            // E / CHUNK
#define EPT 4
#define GPB (TPB/4)          // pairs per block per k-iter = 64
#define CHUNK (GPB*EPT)      // 256 pairs per block, locally type-sorted
#define W0S 528              // per-type float stride: 528/4=132 == 4 (mod 32) -> even quad spread
#define W1S 260              // per-type float stride for sW1 (256 + 4 pad)

__device__ __forceinline__ float silu_f(float x) {
    return x / (1.0f + __expf(-x));
}

// ---- deterministic per-chunk counting sort by pair type (parallel rank scan) ----
// perm[chunk slot] = pair_index | (type << 20). Stable within chunk.
__global__ __launch_bounds__(TPB)
void nep_sort(const int* __restrict__ ij, int* __restrict__ perm)
{
    __shared__ unsigned char sty[CHUNK];
    __shared__ int soff[16];
    const int tid = threadIdx.x;
    const int base = blockIdx.x * CHUNK;
    const int t = ij[base + tid];
    sty[tid] = (unsigned char)t;
    __syncthreads();
    // rank of this slot among equal-type earlier slots (full uchar4 scan)
    const uchar4* s4 = (const uchar4*)sty;
    int rank = 0;
    #pragma unroll 8
    for (int j4 = 0; j4 < CHUNK / 4; j4++) {
        uchar4 v = s4[j4];
        int j = j4 * 4;
        rank += ((v.x == t) & (j + 0 < tid)) + ((v.y == t) & (j + 1 < tid))
              + ((v.z == t) & (j + 2 < tid)) + ((v.w == t) & (j + 3 < tid));
    }
    // per-type totals (threads 0..15), then exclusive prefix (thread 0)
    if (tid < 16) {
        int c = 0;
        #pragma unroll 8
        for (int j4 = 0; j4 < CHUNK / 4; j4++) {
            uchar4 v = s4[j4];
            c += (v.x == tid) + (v.y == tid) + (v.z == tid) + (v.w == tid);
        }
        soff[tid] = c;
    }
    __syncthreads();
    if (tid == 0) {
        int acc = 0;
        #pragma unroll
        for (int tt = 0; tt < 16; tt++) { int c = soff[tt]; soff[tt] = acc; acc += c; }
    }
    __syncthreads();
    perm[base + soff[t] + rank] = (base + tid) | (t << 20);
}

// 4 lanes cooperate on one pair; lane (tid&3) owns channels h = lane*8 .. lane*8+7.
// Pairs visited in type-sorted order -> wave-uniform types -> W0/W1 LDS reads broadcast.
template<int PHASE>
__global__ __launch_bounds__(TPB, 4)
void nep_main(const int* __restrict__ perm,
              const float* __restrict__ fn,
              const float* __restrict__ W0g,
              const float* __restrict__ W1g,
              const float* __restrict__ ab1,
              const float* __restrict__ ab2,
              float* __restrict__ partial,
              float* __restrict__ out)
{
    __shared__ __align__(16) float sW0[16 * W0S];
    __shared__ __align__(16) float sW1[(PHASE >= 1) ? 16 * W1S : 4];
    __shared__ float sAB1[64];
    __shared__ float sAB2[16];
    __shared__ float sredS[4][32];
    __shared__ float sredQ[4][32];

    const int tid = threadIdx.x;
    const int bid = blockIdx.x;
    const int lane4 = tid & 3;
    const int grp = tid >> 2;

    // Stage W0 -> LDS, XOR block swizzle (reader lane4 k reads block j^k).
    {
        const float4* W04 = (const float4*)W0g;
        #pragma unroll
        for (int i = 0; i < 8; i++) {
            int g4 = tid + i * TPB;              // 0..2047
            float4 v = W04[g4];
            int t = g4 >> 7;
            int h = (g4 >> 2) & 31;
            int j = g4 & 3;
            int js = j ^ ((h >> 3) & 3);
            *(float4*)&sW0[t * W0S + h * 16 + js * 4] = v;
        }
    }
    if constexpr (PHASE >= 1) {
        // W1 global [t][n][h] -> LDS [t][(h&7)*32 + (h>>3)*8 + n]
        const float4* W14 = (const float4*)W1g;
        #pragma unroll
        for (int i = 0; i < 4; i++) {
            int g4 = tid + i * TPB;              // 0..1023
            float4 v = W14[g4];
            int g = g4 * 4;
            int t = g >> 8;
            int n = (g >> 5) & 7;
            int h0 = g & 31;
            #pragma unroll
            for (int dd = 0; dd < 4; dd++) {
                int h = h0 + dd;
                float val = (dd == 0) ? v.x : (dd == 1) ? v.y : (dd == 2) ? v.z : v.w;
                sW1[t * W1S + (h & 7) * 32 + (h >> 3) * 8 + n] = val;
            }
        }
        if (tid < 64) sAB1[tid] = ab1[tid];
    }
    if constexpr (PHASE == 2) {
        if (tid < 16) sAB2[tid] = ab2[tid];
    }
    __syncthreads();

    float abA[8], abB[8];
    if constexpr (PHASE >= 1) {
        #pragma unroll
        for (int c = 0; c < 8; c++) {
            abA[c] = sAB1[lane4 * 8 + c];
            abB[c] = sAB1[32 + lane4 * 8 + c];
        }
    }
    float a2A[8], a2B[8];
    if constexpr (PHASE == 2) {
        #pragma unroll
        for (int n = 0; n < 8; n++) { a2A[n] = sAB2[n]; a2B[n] = sAB2[8 + n]; }
    }

    float s1[8], s2[8];
    #pragma unroll
    for (int c = 0; c < 8; c++) { s1[c] = 0.f; s2[c] = 0.f; }

    // two-deep pipeline: perm 2 ahead, fn 1 ahead
    const int sl = bid * CHUNK + grp;
    int pvA = perm[sl];
    int pvB = perm[sl + GPB];
    int qA0 = pvA & 0xFFFFF;
    const float4* f40 = (const float4*)(fn + (size_t)qA0 * 16);
    float4 fa = f40[0], fb = f40[1], fc = f40[2], fd = f40[3];

    #pragma unroll 1
    for (int k = 0; k < EPT; k++) {
        const int t = pvA >> 20;
        const int q = pvA & 0xFFFFF;

        int pvC = pvB;
        if (k + 2 < EPT) pvC = perm[sl + (k + 2) * GPB];
        float4 na = fa, nb = fb, nc = fc, nd = fd;
        if (k + 1 < EPT) {
            int qn = pvB & 0xFFFFF;
            const float4* g4p = (const float4*)(fn + (size_t)qn * 16);
            na = g4p[0]; nb = g4p[1]; nc = g4p[2]; nd = g4p[3];
        }

        const float* w0t = &sW0[t * W0S];

        float o2[8];
        if constexpr (PHASE >= 1) {
            #pragma unroll
            for (int n = 0; n < 8; n++) o2[n] = 0.f;
        }

        #pragma unroll
        for (int hh = 0; hh < 8; hh++) {
            const int h = lane4 * 8 + hh;
            const float* wr = w0t + h * 16;
            const int x = lane4;                 // == (h>>3)&3
            float4 wA = *(const float4*)(wr + ((0 ^ x) << 2));
            float4 wB = *(const float4*)(wr + ((1 ^ x) << 2));
            float4 wC = *(const float4*)(wr + ((2 ^ x) << 2));
            float4 wD = *(const float4*)(wr + ((3 ^ x) << 2));
            float d = wA.x * fa.x + wA.y * fa.y + wA.z * fa.z + wA.w * fa.w
                    + wB.x * fb.x + wB.y * fb.y + wB.z * fb.z + wB.w * fb.w
                    + wC.x * fc.x + wC.y * fc.y + wC.z * fc.z + wC.w * fc.w
                    + wD.x * fd.x + wD.y * fd.y + wD.z * fd.z + wD.w * fd.w;
            if constexpr (PHASE == 0) {
                s1[hh] += d;
                s2[hh] += d * d;
            } else {
                float xv = abA[hh] * d + abB[hh];
                float a = silu_f(xv);
                const float* wn = &sW1[t * W1S + hh * 32 + lane4 * 8];
                float4 pA = *(const float4*)(wn);
                float4 pB = *(const float4*)(wn + 4);
                o2[0] += pA.x * a; o2[1] += pA.y * a; o2[2] += pA.z * a; o2[3] += pA.w * a;
                o2[4] += pB.x * a; o2[5] += pB.y * a; o2[6] += pB.z * a; o2[7] += pB.w * a;
            }
        }

        if constexpr (PHASE >= 1) {
            #pragma unroll
            for (int n = 0; n < 8; n++) {
                o2[n] += __shfl_xor(o2[n], 1, 64);
                o2[n] += __shfl_xor(o2[n], 2, 64);
            }
        }
        if constexpr (PHASE == 1) {
            if (lane4 == 0) {
                #pragma unroll
                for (int n = 0; n < 8; n++) { s1[n] += o2[n]; s2[n] += o2[n] * o2[n]; }
            }
        }
        if constexpr (PHASE == 2) {
            float r0 = silu_f(a2A[0] * o2[0] + a2B[0]);
            float r1 = silu_f(a2A[1] * o2[1] + a2B[1]);
            float r2 = silu_f(a2A[2] * o2[2] + a2B[2]);
            float r3 = silu_f(a2A[3] * o2[3] + a2B[3]);
            float r4 = silu_f(a2A[4] * o2[4] + a2B[4]);
            float r5 = silu_f(a2A[5] * o2[5] + a2B[5]);
            float r6 = silu_f(a2A[6] * o2[6] + a2B[6]);
            float r7 = silu_f(a2A[7] * o2[7] + a2B[7]);
            float e0 = (lane4 == 0) ? r0 : (lane4 == 1) ? r2 : (lane4 == 2) ? r4 : r6;
            float e1 = (lane4 == 0) ? r1 : (lane4 == 1) ? r3 : (lane4 == 2) ? r5 : r7;
            *(float2*)(out + (size_t)q * 8 + lane4 * 2) = make_float2(e0, e1);
        }

        pvA = pvB; pvB = pvC;
        fa = na; fb = nb; fc = nc; fd = nd;
    }

    if constexpr (PHASE == 0) {
        #pragma unroll
        for (int c = 0; c < 8; c++) {
            float v1 = s1[c], v2 = s2[c];
            v1 += __shfl_xor(v1, 4, 64);  v2 += __shfl_xor(v2, 4, 64);
            v1 += __shfl_xor(v1, 8, 64);  v2 += __shfl_xor(v2, 8, 64);
            v1 += __shfl_xor(v1, 16, 64); v2 += __shfl_xor(v2, 16, 64);
            v1 += __shfl_xor(v1, 32, 64); v2 += __shfl_xor(v2, 32, 64);
            s1[c] = v1; s2[c] = v2;
        }
        const int wid = tid >> 6;
        if ((tid & 63) < 4) {
            #pragma unroll
            for (int c = 0; c < 8; c++) {
                sredS[wid][lane4 * 8 + c] = s1[c];
                sredQ[wid][lane4 * 8 + c] = s2[c];
            }
        }
        __syncthreads();
        if (tid < 32) {
            float a = sredS[0][tid] + sredS[1][tid] + sredS[2][tid] + sredS[3][tid];
            float b = sredQ[0][tid] + sredQ[1][tid] + sredQ[2][tid] + sredQ[3][tid];
            partial[bid * 64 + tid]      = a;
            partial[bid * 64 + 32 + tid] = b;
        }
    }
    if constexpr (PHASE == 1) {
        #pragma unroll
        for (int c = 0; c < 8; c++) {
            float v1 = s1[c], v2 = s2[c];
            v1 += __shfl_xor(v1, 4, 64);  v2 += __shfl_xor(v2, 4, 64);
            v1 += __shfl_xor(v1, 8, 64);  v2 += __shfl_xor(v2, 8, 64);
            v1 += __shfl_xor(v1, 16, 64); v2 += __shfl_xor(v2, 16, 64);
            v1 += __shfl_xor(v1, 32, 64); v2 += __shfl_xor(v2, 32, 64);
            s1[c] = v1; s2[c] = v2;
        }
        const int wid = tid >> 6;
        if ((tid & 63) == 0) {
            #pragma unroll
            for (int n = 0; n < 8; n++) { sredS[wid][n] = s1[n]; sredQ[wid][n] = s2[n]; }
        }
        __syncthreads();
        if (tid < 8) {
            float a = sredS[0][tid] + sredS[1][tid] + sredS[2][tid] + sredS[3][tid];
            float b = sredQ[0][tid] + sredQ[1][tid] + sredQ[2][tid] + sredQ[3][tid];
            partial[bid * 16 + tid]     = a;
            partial[bid * 16 + 8 + tid] = b;
        }
    }
}

// Reduce block partials; fold mean/var + gamma/beta into per-channel affine (a,b).
template<int NS, int JW>
__global__ void nep_finalize(const float* __restrict__ partial,
                             const float* __restrict__ gamma,
                             const float* __restrict__ beta,
                             const int* __restrict__ norm,
                             float* __restrict__ ab)
{
    __shared__ float ssum[JW][NS];
    __shared__ float ssq[JW][NS];
    const int c = threadIdx.x & (NS - 1);
    const int j = threadIdx.x / NS;
    float s = 0.f, q = 0.f;
    for (int blk = j; blk < NBLK; blk += JW) {
        s += partial[blk * (2 * NS) + c];
        q += partial[blk * (2 * NS) + NS + c];
    }
    ssum[j][c] = s; ssq[j][c] = q;
    __syncthreads();
    if (threadIdx.x < NS) {
        float st = 0.f, qt = 0.f;
        #pragma unroll
        for (int jj = 0; jj < JW; jj++) { st += ssum[jj][c]; qt += ssq[jj][c]; }
        const float invE = 1.0f / (float)E_TOTAL;
        float mean = st * invE;
        float var  = qt * invE - mean * mean;
        float inv  = rsqrtf(var + 1e-5f);
        float a, b;
        if (*norm) {
            a = gamma[c] * inv;
            b = beta[c] - mean * a;
        } else {
            a = 1.f; b = 0.f;
        }
        ab[c] = a;
        ab[NS + c] = b;
    }
}

extern "C" void kernel_launch(void* const* d_in, const int* in_sizes, int n_in,
                              void* d_out, int out_size, void* d_ws, size_t ws_size,
                              hipStream_t stream)
{
    const int*   ij   = (const int*)d_in[0];
    const float* fn   = (const float*)d_in[1];
    const float* W0   = (const float*)d_in[2];
    const float* W1   = (const float*)d_in[3];
    const float* g1   = (const float*)d_in[4];
    const float* b1   = (const float*)d_in[5];
    const float* g2   = (const float*)d_in[6];
    const float* b2   = (const float*)d_in[7];
    const int*   norm = (const int*)d_in[8];
    float* out = (float*)d_out;

    int*   perm = (int*)d_ws;                        // E ints (1 MB)
    float* p1  = (float*)(perm + E_TOTAL);           // NBLK * 64 floats
    float* p2  = p1 + NBLK * 64;                     // NBLK * 16 floats
    float* ab1 = p2 + NBLK * 16;                     // 64 floats
    float* ab2 = ab1 + 64;                           // 16 floats

    nep_sort<<<NBLK, TPB, 0, stream>>>(ij, perm);

    nep_main<0><<<NBLK, TPB, 0, stream>>>(perm, fn, W0, W1, nullptr, nullptr, p1, nullptr);
    nep_finalize<32, 16><<<1, 512, 0, stream>>>(p1, g1, b1, norm, ab1);
    nep_main<1><<<NBLK, TPB, 0, stream>>>(perm, fn, W0, W1, ab1, nullptr, p2, nullptr);
    nep_finalize<8, 32><<<1, 256, 0, stream>>>(p2, g2, b2, norm, ab2);
    nep_main<2><<<NBLK, TPB, 0, stream>>>(perm, fn, W0, W1, ab1, ab2, nullptr, out);
}

// Round 8
// 78.289 us; speedup vs baseline: 3.1070x; 1.2036x over previous
//
#include <hip/hip_runtime.h>

#define E_TOTAL 262144
#define TPB 256
#define NBLK 1024            // E / CHUNK
#define EPT 4
#define GPB (TPB/4)          // pairs per block per k-iter = 64
#define CHUNK (GPB*EPT)      // 256 pairs per block, locally type-sorted
#define W0S 528              // per-type float stride: 132 quads == 4 (mod 32) -> even spread
#define W1S 260              // per-type float stride for sW1

__device__ __forceinline__ float silu_f(float x) {
    return x / (1.0f + __expf(-x));
}

// PHASE 0: inline chunk-sort (LDS) -> BN1 stats of out1; writes perm for phase 1.
// PHASE 1: read perm, recompute out1, BN1+SiLU, second matvec -> write pre-BN2 o2
//          to out; accumulate BN2 stats.
template<int PHASE>
__global__ __launch_bounds__(TPB, 4)
void nep_main(const int* __restrict__ ij,
              int* __restrict__ perm,
              const float* __restrict__ fn,
              const float* __restrict__ W0g,
              const float* __restrict__ W1g,
              const float* __restrict__ ab1,
              float* __restrict__ partial,
              float* __restrict__ out)
{
    __shared__ __align__(16) float sW0[16 * W0S];
    __shared__ __align__(16) float sW1[(PHASE >= 1) ? 16 * W1S : 4];
    __shared__ float sAB1[64];
    __shared__ float sredS[4][32];
    __shared__ float sredQ[4][32];
    __shared__ unsigned char sty[(PHASE == 0) ? CHUNK : 4];
    __shared__ int soff[16];
    __shared__ int sperm[(PHASE == 0) ? CHUNK : 4];

    const int tid = threadIdx.x;
    const int bid = blockIdx.x;
    const int lane4 = tid & 3;
    const int grp = tid >> 2;
    const int base = bid * CHUNK;

    // ---- inline deterministic counting sort of this block's chunk (PHASE 0) ----
    if constexpr (PHASE == 0) {
        const int t0 = ij[base + tid];
        sty[tid] = (unsigned char)t0;
        __syncthreads();
        const uchar4* s4 = (const uchar4*)sty;
        int rank = 0;
        #pragma unroll 8
        for (int j4 = 0; j4 < CHUNK / 4; j4++) {
            uchar4 v = s4[j4];
            int j = j4 * 4;
            rank += ((v.x == t0) & (j + 0 < tid)) + ((v.y == t0) & (j + 1 < tid))
                  + ((v.z == t0) & (j + 2 < tid)) + ((v.w == t0) & (j + 3 < tid));
        }
        if (tid < 16) {
            int c = 0;
            #pragma unroll 8
            for (int j4 = 0; j4 < CHUNK / 4; j4++) {
                uchar4 v = s4[j4];
                c += (v.x == tid) + (v.y == tid) + (v.z == tid) + (v.w == tid);
            }
            soff[tid] = c;
        }
        __syncthreads();
        if (tid == 0) {
            int acc = 0;
            #pragma unroll
            for (int tt = 0; tt < 16; tt++) { int c = soff[tt]; soff[tt] = acc; acc += c; }
        }
        __syncthreads();
        sperm[soff[t0] + rank] = tid | (t0 << 20);
    }

    // ---- stage W0 -> LDS, XOR block swizzle ----
    {
        const float4* W04 = (const float4*)W0g;
        #pragma unroll
        for (int i = 0; i < 8; i++) {
            int g4 = tid + i * TPB;              // 0..2047
            float4 v = W04[g4];
            int t = g4 >> 7;
            int h = (g4 >> 2) & 31;
            int j = g4 & 3;
            int js = j ^ ((h >> 3) & 3);
            *(float4*)&sW0[t * W0S + h * 16 + js * 4] = v;
        }
    }
    if constexpr (PHASE >= 1) {
        // W1 global [t][n][h] -> LDS [t][(h&7)*32 + (h>>3)*8 + n]
        const float4* W14 = (const float4*)W1g;
        #pragma unroll
        for (int i = 0; i < 4; i++) {
            int g4 = tid + i * TPB;              // 0..1023
            float4 v = W14[g4];
            int g = g4 * 4;
            int t = g >> 8;
            int n = (g >> 5) & 7;
            int h0 = g & 31;
            #pragma unroll
            for (int dd = 0; dd < 4; dd++) {
                int h = h0 + dd;
                float val = (dd == 0) ? v.x : (dd == 1) ? v.y : (dd == 2) ? v.z : v.w;
                sW1[t * W1S + (h & 7) * 32 + (h >> 3) * 8 + n] = val;
            }
        }
        if (tid < 64) sAB1[tid] = ab1[tid];
    }
    __syncthreads();

    // PHASE 0: publish perm for phase 1 (coalesced; base fits low-20-bit field)
    if constexpr (PHASE == 0) {
        perm[base + tid] = sperm[tid] + base;
    }

    float abA[8], abB[8];
    if constexpr (PHASE >= 1) {
        #pragma unroll
        for (int c = 0; c < 8; c++) {
            abA[c] = sAB1[lane4 * 8 + c];
            abB[c] = sAB1[32 + lane4 * 8 + c];
        }
    }

    float s1[8], s2[8];
    #pragma unroll
    for (int c = 0; c < 8; c++) { s1[c] = 0.f; s2[c] = 0.f; }

    // two-deep pipeline: perm 2 ahead, fn 1 ahead
    int pvA, pvB;
    if constexpr (PHASE == 0) {
        pvA = sperm[grp];
        pvB = sperm[GPB + grp];
    } else {
        pvA = perm[base + grp] - base;           // local-form: low field = local idx
        pvB = perm[base + GPB + grp] - base;
    }
    {
        int q0 = base + (pvA & 0xFFFFF);
        const float4* f40 = (const float4*)(fn + (size_t)q0 * 16);
        float4 f0 = f40[0], f1 = f40[1], f2 = f40[2], f3 = f40[3];

        float4 fa = f0, fb = f1, fc = f2, fd = f3;

        #pragma unroll 1
        for (int k = 0; k < EPT; k++) {
            const int t = pvA >> 20;
            const int q = base + (pvA & 0xFFFFF);

            int pvC = pvB;
            if (k + 2 < EPT) {
                if constexpr (PHASE == 0) pvC = sperm[(k + 2) * GPB + grp];
                else                      pvC = perm[base + (k + 2) * GPB + grp] - base;
            }
            float4 na = fa, nb = fb, nc = fc, nd = fd;
            if (k + 1 < EPT) {
                int qn = base + (pvB & 0xFFFFF);
                const float4* g4p = (const float4*)(fn + (size_t)qn * 16);
                na = g4p[0]; nb = g4p[1]; nc = g4p[2]; nd = g4p[3];
            }

            const float* w0t = &sW0[t * W0S];

            float o2[8];
            if constexpr (PHASE >= 1) {
                #pragma unroll
                for (int n = 0; n < 8; n++) o2[n] = 0.f;
            }

            #pragma unroll
            for (int hh = 0; hh < 8; hh++) {
                const int h = lane4 * 8 + hh;
                const float* wr = w0t + h * 16;
                const int x = lane4;             // == (h>>3)&3
                float4 wA = *(const float4*)(wr + ((0 ^ x) << 2));
                float4 wB = *(const float4*)(wr + ((1 ^ x) << 2));
                float4 wC = *(const float4*)(wr + ((2 ^ x) << 2));
                float4 wD = *(const float4*)(wr + ((3 ^ x) << 2));
                float d = wA.x * fa.x + wA.y * fa.y + wA.z * fa.z + wA.w * fa.w
                        + wB.x * fb.x + wB.y * fb.y + wB.z * fb.z + wB.w * fb.w
                        + wC.x * fc.x + wC.y * fc.y + wC.z * fc.z + wC.w * fc.w
                        + wD.x * fd.x + wD.y * fd.y + wD.z * fd.z + wD.w * fd.w;
                if constexpr (PHASE == 0) {
                    s1[hh] += d;
                    s2[hh] += d * d;
                } else {
                    float xv = abA[hh] * d + abB[hh];
                    float a = silu_f(xv);
                    const float* wn = &sW1[t * W1S + hh * 32 + lane4 * 8];
                    float4 pA = *(const float4*)(wn);
                    float4 pB = *(const float4*)(wn + 4);
                    o2[0] += pA.x * a; o2[1] += pA.y * a; o2[2] += pA.z * a; o2[3] += pA.w * a;
                    o2[4] += pB.x * a; o2[5] += pB.y * a; o2[6] += pB.z * a; o2[7] += pB.w * a;
                }
            }

            if constexpr (PHASE >= 1) {
                #pragma unroll
                for (int n = 0; n < 8; n++) {
                    o2[n] += __shfl_xor(o2[n], 1, 64);
                    o2[n] += __shfl_xor(o2[n], 2, 64);
                }
                if (lane4 == 0) {
                    #pragma unroll
                    for (int n = 0; n < 8; n++) { s1[n] += o2[n]; s2[n] += o2[n] * o2[n]; }
                }
                // write pre-BN2 o2 to out (final affine+SiLU applied by nep_bn2)
                float e0 = (lane4 == 0) ? o2[0] : (lane4 == 1) ? o2[2] : (lane4 == 2) ? o2[4] : o2[6];
                float e1 = (lane4 == 0) ? o2[1] : (lane4 == 1) ? o2[3] : (lane4 == 2) ? o2[5] : o2[7];
                *(float2*)(out + (size_t)q * 8 + lane4 * 2) = make_float2(e0, e1);
            }

            pvA = pvB; pvB = pvC;
            fa = na; fb = nb; fc = nc; fd = nd;
        }
    }

    if constexpr (PHASE == 0) {
        #pragma unroll
        for (int c = 0; c < 8; c++) {
            float v1 = s1[c], v2 = s2[c];
            v1 += __shfl_xor(v1, 4, 64);  v2 += __shfl_xor(v2, 4, 64);
            v1 += __shfl_xor(v1, 8, 64);  v2 += __shfl_xor(v2, 8, 64);
            v1 += __shfl_xor(v1, 16, 64); v2 += __shfl_xor(v2, 16, 64);
            v1 += __shfl_xor(v1, 32, 64); v2 += __shfl_xor(v2, 32, 64);
            s1[c] = v1; s2[c] = v2;
        }
        const int wid = tid >> 6;
        if ((tid & 63) < 4) {
            #pragma unroll
            for (int c = 0; c < 8; c++) {
                sredS[wid][lane4 * 8 + c] = s1[c];
                sredQ[wid][lane4 * 8 + c] = s2[c];
            }
        }
        __syncthreads();
        if (tid < 32) {
            float a = sredS[0][tid] + sredS[1][tid] + sredS[2][tid] + sredS[3][tid];
            float b = sredQ[0][tid] + sredQ[1][tid] + sredQ[2][tid] + sredQ[3][tid];
            partial[bid * 64 + tid]      = a;
            partial[bid * 64 + 32 + tid] = b;
        }
    }
    if constexpr (PHASE == 1) {
        #pragma unroll
        for (int c = 0; c < 8; c++) {
            float v1 = s1[c], v2 = s2[c];
            v1 += __shfl_xor(v1, 4, 64);  v2 += __shfl_xor(v2, 4, 64);
            v1 += __shfl_xor(v1, 8, 64);  v2 += __shfl_xor(v2, 8, 64);
            v1 += __shfl_xor(v1, 16, 64); v2 += __shfl_xor(v2, 16, 64);
            v1 += __shfl_xor(v1, 32, 64); v2 += __shfl_xor(v2, 32, 64);
            s1[c] = v1; s2[c] = v2;
        }
        const int wid = tid >> 6;
        if ((tid & 63) == 0) {
            #pragma unroll
            for (int n = 0; n < 8; n++) { sredS[wid][n] = s1[n]; sredQ[wid][n] = s2[n]; }
        }
        __syncthreads();
        if (tid < 8) {
            float a = sredS[0][tid] + sredS[1][tid] + sredS[2][tid] + sredS[3][tid];
            float b = sredQ[0][tid] + sredQ[1][tid] + sredQ[2][tid] + sredQ[3][tid];
            partial[bid * 16 + tid]     = a;
            partial[bid * 16 + 8 + tid] = b;
        }
    }
}

// Reduce block partials; fold mean/var + gamma/beta into per-channel affine (a,b).
template<int NS, int JW>
__global__ void nep_finalize(const float* __restrict__ partial,
                             const float* __restrict__ gamma,
                             const float* __restrict__ beta,
                             const int* __restrict__ norm,
                             float* __restrict__ ab)
{
    __shared__ float ssum[JW][NS];
    __shared__ float ssq[JW][NS];
    const int c = threadIdx.x & (NS - 1);
    const int j = threadIdx.x / NS;
    float s = 0.f, q = 0.f;
    for (int blk = j; blk < NBLK; blk += JW) {
        s += partial[blk * (2 * NS) + c];
        q += partial[blk * (2 * NS) + NS + c];
    }
    ssum[j][c] = s; ssq[j][c] = q;
    __syncthreads();
    if (threadIdx.x < NS) {
        float st = 0.f, qt = 0.f;
        #pragma unroll
        for (int jj = 0; jj < JW; jj++) { st += ssum[jj][c]; qt += ssq[jj][c]; }
        const float invE = 1.0f / (float)E_TOTAL;
        float mean = st * invE;
        float var  = qt * invE - mean * mean;
        float inv  = rsqrtf(var + 1e-5f);
        float a, b;
        if (*norm) {
            a = gamma[c] * inv;
            b = beta[c] - mean * a;
        } else {
            a = 1.f; b = 0.f;
        }
        ab[c] = a;
        ab[NS + c] = b;
    }
}

// Streaming epilogue: out[i] = silu(a2[i&7]*out[i] + b2[i&7]), float4-vectorized.
__global__ __launch_bounds__(TPB)
void nep_bn2(float* __restrict__ out, const float* __restrict__ ab2)
{
    __shared__ float sA[8], sB[8];
    if (threadIdx.x < 8) { sA[threadIdx.x] = ab2[threadIdx.x]; sB[threadIdx.x] = ab2[8 + threadIdx.x]; }
    __syncthreads();
    const int i = blockIdx.x * TPB + threadIdx.x;     // float4 index, 524288 total
    float4 v = ((const float4*)out)[i];
    const int c0 = (i & 1) * 4;                        // channels c0..c0+3
    float a0 = sA[c0], a1 = sA[c0 + 1], a2 = sA[c0 + 2], a3 = sA[c0 + 3];
    float b0 = sB[c0], b1 = sB[c0 + 1], b2 = sB[c0 + 2], b3 = sB[c0 + 3];
    v.x = silu_f(a0 * v.x + b0);
    v.y = silu_f(a1 * v.y + b1);
    v.z = silu_f(a2 * v.z + b2);
    v.w = silu_f(a3 * v.w + b3);
    ((float4*)out)[i] = v;
}

extern "C" void kernel_launch(void* const* d_in, const int* in_sizes, int n_in,
                              void* d_out, int out_size, void* d_ws, size_t ws_size,
                              hipStream_t stream)
{
    const int*   ij   = (const int*)d_in[0];
    const float* fn   = (const float*)d_in[1];
    const float* W0   = (const float*)d_in[2];
    const float* W1   = (const float*)d_in[3];
    const float* g1   = (const float*)d_in[4];
    const float* b1   = (const float*)d_in[5];
    const float* g2   = (const float*)d_in[6];
    const float* b2   = (const float*)d_in[7];
    const int*   norm = (const int*)d_in[8];
    float* out = (float*)d_out;

    int*   perm = (int*)d_ws;                        // E ints (1 MB)
    float* p1  = (float*)(perm + E_TOTAL);           // NBLK * 64 floats
    float* p2  = p1 + NBLK * 64;                     // NBLK * 16 floats
    float* ab1 = p2 + NBLK * 16;                     // 64 floats
    float* ab2 = ab1 + 64;                           // 16 floats

    nep_main<0><<<NBLK, TPB, 0, stream>>>(ij, perm, fn, W0, W1, nullptr, p1, nullptr);
    nep_finalize<32, 16><<<1, 512, 0, stream>>>(p1, g1, b1, norm, ab1);
    nep_main<1><<<NBLK, TPB, 0, stream>>>(ij, perm, fn, W0, W1, ab1, p2, out);
    nep_finalize<8, 32><<<1, 256, 0, stream>>>(p2, g2, b2, norm, ab2);
    nep_bn2<<<(E_TOTAL * 8 / 4) / TPB, TPB, 0, stream>>>(out, ab2);
}